// Round 9
// baseline (249.461 us; speedup 1.0000x reference)
//
#include <hip/hip_runtime.h>
#include <stdint.h>

typedef unsigned short u16;
typedef __bf16 bf16x8 __attribute__((ext_vector_type(8)));
typedef float f32x4 __attribute__((ext_vector_type(4)));

__device__ __forceinline__ u16 f2bf(float f) {
  union { float f; uint32_t u; } x; x.f = f;
  uint32_t u = x.u;
  u += 0x7fffu + ((u >> 16) & 1u);   // round-to-nearest-even
  return (u16)(u >> 16);
}
__device__ __forceinline__ float bf2f(uint32_t lo16) {
  union { uint32_t u; float f; } x; x.u = lo16 << 16; return x.f;
}
__device__ __forceinline__ float bfhi(uint32_t u) {
  union { uint32_t u; float f; } x; x.u = u & 0xffff0000u; return x.f;
}
// fix one bf16 pair: e_k = m_k + p_k * F_k, repacked to bf16x2
__device__ __forceinline__ uint32_t fixpair(uint32_t m, float p0, float p1,
                                            float F0, float F1) {
  float e0 = fmaf(p0, F0, bf2f(m & 0xffffu));
  float e1 = fmaf(p1, F1, bfhi(m));
  return (uint32_t)f2bf(e0) | ((uint32_t)f2bf(e1) << 16);
}

__device__ __forceinline__ void async_load16(const u16* g, u16* l) {
  __builtin_amdgcn_global_load_lds(
      (const __attribute__((address_space(1))) void*)g,
      (__attribute__((address_space(3))) void*)l,
      16, 0, 0);
}

// ---------------- prep_all: sigmoid(beta)+bpow table + weight/x converts ----------------
// bpow[p][h] = beta_h^p for p = 1..32 (fp32, 132 KB, L2-resident).
__global__ __launch_bounds__(256) void prep_all(const float* __restrict__ x,
                                                const float* __restrict__ Wq,
                                                const float* __restrict__ Wfc,
                                                const float* __restrict__ braw,
                                                u16* __restrict__ xb,
                                                u16* __restrict__ wqb,
                                                u16* __restrict__ wfcb,
                                                float* __restrict__ beta,
                                                float* __restrict__ bpow) {
  int gid = blockIdx.x * 256 + threadIdx.x;
  if (gid < 1024) {
    float b = 1.0f / (1.0f + expf(-braw[gid]));
    beta[gid] = b;
    float w = b;
#pragma unroll 1
    for (int p = 1; p <= 32; p++) { bpow[p * 1024 + gid] = w; w *= b; }
  }
  if (gid < 131072) {
    const int HH = 1024 * 1024;
    int i = gid * 16;
    const float* src = (i < HH) ? (Wq + i) : (Wfc + (i - HH));
    u16* dst = (i < HH) ? (wqb + i) : (wfcb + (i - HH));
#pragma unroll
    for (int c = 0; c < 4; c++) {
      float4 v = *(const float4*)(src + c * 4);
      ushort4 o = {f2bf(v.x), f2bf(v.y), f2bf(v.z), f2bf(v.w)};
      *(ushort4*)(dst + c * 4) = o;
    }
  }
  {
    int i = gid * 8;
    float4 a = *(const float4*)(x + i);
    float4 b = *(const float4*)(x + i + 4);
    ushort4 o0 = {f2bf(a.x), f2bf(a.y), f2bf(a.z), f2bf(a.w)};
    ushort4 o1 = {f2bf(b.x), f2bf(b.y), f2bf(b.z), f2bf(b.w)};
    *(ushort4*)(xb + i) = o0;
    *(ushort4*)(xb + i + 4) = o1;
  }
}

// ---------------- GEMM1 + fused segment-local scan: m_local = localscan(x Wq^T + b) ----
// Ring schedule = R1/R4 harness-verified (256x256 tile, BK=32, 4-deep LDS ring,
// counted vmcnt(8), XCD swizzle). Epilogue computes the FULL segment-local scan
// in-register (one block = one 32t x 8b segment) and writes bf16 m_local + the
// segment carry m(31). fp32 q feeds the scan.
__global__ __launch_bounds__(512, 2) void gemm_scan(const u16* __restrict__ A,
                                                    const u16* __restrict__ B,
                                                    const float* __restrict__ bias,
                                                    u16* __restrict__ Cout,
                                                    const float* __restrict__ beta_arr,
                                                    float* __restrict__ carry_out,
                                                    int M, int N, int K) {
  __shared__ u16 lds[4][2][256 * 32];  // 128 KiB ring

  const int tid  = threadIdx.x;
  const int lane = tid & 63;
  const int wid  = tid >> 6;
  const int wr   = (wid >> 2) * 128;
  const int wc   = (wid & 3) * 64;

  const int bid    = blockIdx.x;
  const int xcd    = bid & 7;
  const int idx    = bid >> 3;
  const int tile_m = ((xcd << 3) | (idx >> 2)) * 256;
  const int tile_n = (idx & 3) * 256;

  const int srow    = tid >> 2;
  const int schunk  = (tid & 3) ^ ((srow >> 1) & 3);
  const u16* gA = A + (size_t)(tile_m + srow) * K + schunk * 8;
  const u16* gB = B + (size_t)(tile_n + srow) * K + schunk * 8;
  const size_t half_stride = (size_t)128 * K;

#define STAGE(slot, kt)                                                   \
  do {                                                                    \
    const size_t k0 = (size_t)(kt) * 32;                                  \
    async_load16(gA + k0,               &lds[slot][0][wid * 512]);        \
    async_load16(gA + k0 + half_stride, &lds[slot][0][4096 + wid * 512]); \
    async_load16(gB + k0,               &lds[slot][1][wid * 512]);        \
    async_load16(gB + k0 + half_stride, &lds[slot][1][4096 + wid * 512]); \
  } while (0)

  f32x4 acc[8][4];
#pragma unroll
  for (int i = 0; i < 8; i++)
#pragma unroll
    for (int j = 0; j < 4; j++) acc[i][j] = (f32x4){0.f, 0.f, 0.f, 0.f};

  const int lrow = lane & 15;
  const int kq   = lane >> 4;
  const int kc   = (lrow >> 1) & 3;
  const int coff = ((kq ^ kc) << 3);

  const int NKT = K >> 5;  // 32

  STAGE(0, 0);
  if (NKT > 1) STAGE(1, 1);
  if (NKT > 2) STAGE(2, 2);
  if (NKT > 2)      asm volatile("s_waitcnt vmcnt(8)" ::: "memory");
  else if (NKT > 1) asm volatile("s_waitcnt vmcnt(4)" ::: "memory");
  else              asm volatile("s_waitcnt vmcnt(0)" ::: "memory");
  __builtin_amdgcn_s_barrier();

  for (int kt = 0; kt < NKT; ++kt) {
    const int slot = kt & 3;
    const u16* As = &lds[slot][0][0];
    const u16* Bs = &lds[slot][1][0];

    bf16x8 a[8], b[4];
#pragma unroll
    for (int i = 0; i < 8; i++)
      a[i] = *(const bf16x8*)&As[(wr + i * 16 + lrow) * 32 + coff];
#pragma unroll
    for (int j = 0; j < 4; j++)
      b[j] = *(const bf16x8*)&Bs[(wc + j * 16 + lrow) * 32 + coff];

    if (kt + 3 < NKT) STAGE((kt + 3) & 3, kt + 3);

    __builtin_amdgcn_s_setprio(1);
#pragma unroll
    for (int i = 0; i < 8; i++)
#pragma unroll
      for (int j = 0; j < 4; j++)
        acc[i][j] = __builtin_amdgcn_mfma_f32_16x16x32_bf16(a[i], b[j], acc[i][j], 0, 0, 0);
    __builtin_amdgcn_s_setprio(0);

    const int ahead = NKT - 1 - kt;
    if (ahead >= 3) {
      asm volatile("s_waitcnt vmcnt(8)" ::: "memory");
      __builtin_amdgcn_s_barrier();
    } else if (ahead == 2) {
      asm volatile("s_waitcnt vmcnt(4)" ::: "memory");
      __builtin_amdgcn_s_barrier();
    } else if (ahead == 1) {
      asm volatile("s_waitcnt vmcnt(0)" ::: "memory");
      __builtin_amdgcn_s_barrier();
    }
  }
#undef STAGE

  // ---------------- fused segment-local scan epilogue ----------------
  const int crow = (lane >> 4) << 2;
  const int ccol = lane & 15;
  const int c4   = lane >> 4;
  const int kap  = c4 >> 1;
  const int Wh   = wr >> 7;
  float* sm15 = (float*)&lds[0][0][0];  // [8][256] fp32, 8 KB (ring slot 0)

  // Phase A: local (t-half) scan, in place in acc
#pragma unroll
  for (int j = 0; j < 4; j++) {
    const int gn = tile_n + wc + j * 16 + ccol;
    const float bv = bias[gn];
    const float be = beta_arr[gn];
    const float be2 = be * be;
#pragma unroll
    for (int r = 0; r < 4; r++) {
      float S[8], R[8];
      S[0] = acc[0][j][r] + bv;
#pragma unroll
      for (int i = 1; i < 8; i++) S[i] = fmaf(be2, S[i - 1], acc[i][j][r] + bv);
#pragma unroll
      for (int i = 0; i < 8; i++) R[i] = __shfl_xor(S[i], 32);
      acc[0][j][r] = kap ? fmaf(be, R[0], S[0]) : S[0];
#pragma unroll
      for (int i = 1; i < 8; i++)
        acc[i][j][r] = fmaf(be, kap ? R[i] : R[i - 1], S[i]);
    }
  }
  // Phase B: export m(15)
  if (Wh == 0 && kap == 1) {
#pragma unroll
    for (int j = 0; j < 4; j++)
#pragma unroll
      for (int r = 0; r < 4; r++) {
        const int bb = ((c4 << 2) + r) & 7;
        sm15[bb * 256 + wc + j * 16 + ccol] = acc[7][j][r];
      }
  }
  __syncthreads();
  // Phase C: upper half adds beta^{2i+kap+1} * m(15)
  if (Wh == 1) {
#pragma unroll
    for (int j = 0; j < 4; j++) {
      const int hl = wc + j * 16 + ccol;
      const float be = beta_arr[tile_n + hl];
      const float be2 = be * be;
#pragma unroll
      for (int r = 0; r < 4; r++) {
        const int bb = ((c4 << 2) + r) & 7;
        const float v = sm15[bb * 256 + hl];
        float f = kap ? be2 : be;
#pragma unroll
        for (int i = 0; i < 8; i++) {
          acc[i][j][r] = fmaf(f, v, acc[i][j][r]);
          f *= be2;
        }
      }
    }
  }
  // Phase D: store bf16 m_local (+ per-segment carry from registers)
#pragma unroll
  for (int i = 0; i < 8; i++) {
#pragma unroll
    for (int j = 0; j < 4; j++) {
      const int gm = tile_m + wr + i * 16 + crow;
      const int gn = tile_n + wc + j * 16 + ccol;
#pragma unroll
      for (int r = 0; r < 4; r++)
        Cout[(size_t)(gm + r) * N + gn] = f2bf(acc[i][j][r]);
    }
  }
  if (Wh == 1 && kap == 1) {
    const int seg = tile_m >> 8;
#pragma unroll
    for (int j = 0; j < 4; j++) {
      const int hl = wc + j * 16 + ccol;
#pragma unroll
      for (int r = 0; r < 4; r++) {
        const int bb = ((c4 << 2) + r) & 7;
        carry_out[(size_t)seg * 8192 + bb * 1024 + tile_n + hl] = acc[7][j][r];
      }
    }
  }
}

// ---------------- GEMM2 with in-staging scan fixup: relu(m Wfc^T + b) ----------------
// R8: (a) ffold is INLINED into the prologue (each block folds its seg's full
// F slice: 16 floats/thread, <=63 L2 float4 loads + fma; 4 same-seg blocks
// write identical bits to Fbuf -- benign; published via vmcnt(0)+syncthreads).
// (b) iteration reordered so MFMA issues FIRST (needs only auto-lgkm'd frag
// ds_reads); the counted vmcnt + fixup VALU + next A loads sit AFTER the MFMA
// cluster in program order and overlap the matrix pipe (R7 fenced them ahead
// of MFMA -> serialized; MfmaUtil 17%). Fences kept: after STAGE_B2 (vmcnt
// count soundness), after the counted vmcnt (no load hoisting above it),
// rule-18 pair before the end barrier.
// vmcnt(2) at the wait point: outstanding = 8 A-loads (last iter) + 2 B-DMA
// (this iter, newest) -> forces the A-loads and all older B-DMA; B(kt+1)
// (issued 2 iters ago) is therefore always landed before the end barrier.
__global__ __launch_bounds__(512, 1) void gemm_fix(const u16* __restrict__ A,
                                                   const u16* __restrict__ B,
                                                   const float* __restrict__ bias,
                                                   float* __restrict__ Cout,
                                                   const float* __restrict__ bpow,
                                                   const float* __restrict__ carry,
                                                   float* __restrict__ Fbuf,
                                                   int M, int N, int K) {
  __shared__ u16 lds[4][2][256 * 32];  // 128 KiB ring

  const int tid  = threadIdx.x;
  const int lane = tid & 63;
  const int wid  = tid >> 6;
  const int wr   = (wid >> 2) * 128;
  const int wc   = (wid & 3) * 64;

  const int bid    = blockIdx.x;
  const int xcd    = bid & 7;
  const int idx    = bid >> 3;
  const int tile_m = ((xcd << 3) | (idx >> 2)) * 256;
  const int tile_n = (idx & 3) * 256;

  const int srow    = tid >> 2;                    // 0..127
  const int schunk  = (tid & 3) ^ ((srow >> 1) & 3);
  const int t0      = srow >> 3;                   // local t of row0 (0..15)
  const int bb      = srow & 7;                    // batch index of both rows
  const int seg     = tile_m >> 8;

  const u16*   gA2 = A + (size_t)(tile_m + srow) * K + schunk * 8;
  const u16*   gB  = B + (size_t)(tile_n + srow) * K + schunk * 8;
  const float* pb0 = bpow + (size_t)(t0 + 1) * 1024 + schunk * 8;
  const float* fb0 = Fbuf + (size_t)seg * 8192 + bb * 1024 + schunk * 8;
  const size_t half_stride = (size_t)128 * K;

  // ---- inline ffold: F[seg][b][h] = sum_{s<seg} (beta_h^32)^(seg-1-s) carry[s][b][h]
  // 512 thr x 16 floats = full 8x1024 slice; b = tid>>6, h0 = (tid&63)*16.
  {
    const int fb  = tid >> 6;
    const int h0  = (tid & 63) << 4;
    const float4 w0 = *(const float4*)&bpow[32 * 1024 + h0 + 0];
    const float4 w1 = *(const float4*)&bpow[32 * 1024 + h0 + 4];
    const float4 w2 = *(const float4*)&bpow[32 * 1024 + h0 + 8];
    const float4 w3 = *(const float4*)&bpow[32 * 1024 + h0 + 12];
    float4 F0 = {0.f, 0.f, 0.f, 0.f}, F1 = F0, F2 = F0, F3 = F0;
    const float* cb = carry + fb * 1024 + h0;
#pragma unroll 1
    for (int s = 0; s < seg; s++) {
      const float4 c0 = *(const float4*)&cb[(size_t)s * 8192 + 0];
      const float4 c1 = *(const float4*)&cb[(size_t)s * 8192 + 4];
      const float4 c2 = *(const float4*)&cb[(size_t)s * 8192 + 8];
      const float4 c3 = *(const float4*)&cb[(size_t)s * 8192 + 12];
      F0.x = fmaf(w0.x, F0.x, c0.x); F0.y = fmaf(w0.y, F0.y, c0.y);
      F0.z = fmaf(w0.z, F0.z, c0.z); F0.w = fmaf(w0.w, F0.w, c0.w);
      F1.x = fmaf(w1.x, F1.x, c1.x); F1.y = fmaf(w1.y, F1.y, c1.y);
      F1.z = fmaf(w1.z, F1.z, c1.z); F1.w = fmaf(w1.w, F1.w, c1.w);
      F2.x = fmaf(w2.x, F2.x, c2.x); F2.y = fmaf(w2.y, F2.y, c2.y);
      F2.z = fmaf(w2.z, F2.z, c2.z); F2.w = fmaf(w2.w, F2.w, c2.w);
      F3.x = fmaf(w3.x, F3.x, c3.x); F3.y = fmaf(w3.y, F3.y, c3.y);
      F3.z = fmaf(w3.z, F3.z, c3.z); F3.w = fmaf(w3.w, F3.w, c3.w);
    }
    float* fo = Fbuf + (size_t)seg * 8192 + fb * 1024 + h0;
    *(float4*)&fo[0]  = F0;
    *(float4*)&fo[4]  = F1;
    *(float4*)&fo[8]  = F2;
    *(float4*)&fo[12] = F3;
  }
  asm volatile("s_waitcnt vmcnt(0)" ::: "memory");
  __syncthreads();  // publish F (first touch; stores write-through to L2)

  struct ARegs { uint4 m0, m1; float4 p0l, p0h, p1l, p1h, fl, fh; };
  ARegs R;  // single staging set (32 VGPRs)

#define STAGE_B2(slot, kt)                                                \
  do {                                                                    \
    const size_t k0 = (size_t)(kt) * 32;                                  \
    async_load16(gB + k0,               &lds[slot][1][wid * 512]);        \
    async_load16(gB + k0 + half_stride, &lds[slot][1][4096 + wid * 512]); \
  } while (0)

#define LOADA(kt)                                                         \
  do {                                                                    \
    const size_t o = (size_t)(kt) * 32;                                   \
    R.m0  = *(const uint4*)(gA2 + o);                                     \
    R.m1  = *(const uint4*)(gA2 + o + half_stride);                       \
    R.p0l = *(const float4*)(pb0 + o);                                    \
    R.p0h = *(const float4*)(pb0 + o + 4);                                \
    R.p1l = *(const float4*)(pb0 + o + 16384);                            \
    R.p1h = *(const float4*)(pb0 + o + 16388);                            \
    R.fl  = *(const float4*)(fb0 + o);                                    \
    R.fh  = *(const float4*)(fb0 + o + 4);                                \
  } while (0)

#define FIXWRITE(slot)                                                    \
  do {                                                                    \
    uint4 w0, w1;                                                         \
    w0.x = fixpair(R.m0.x, R.p0l.x, R.p0l.y, R.fl.x, R.fl.y);             \
    w0.y = fixpair(R.m0.y, R.p0l.z, R.p0l.w, R.fl.z, R.fl.w);             \
    w0.z = fixpair(R.m0.z, R.p0h.x, R.p0h.y, R.fh.x, R.fh.y);             \
    w0.w = fixpair(R.m0.w, R.p0h.z, R.p0h.w, R.fh.z, R.fh.w);             \
    w1.x = fixpair(R.m1.x, R.p1l.x, R.p1l.y, R.fl.x, R.fl.y);             \
    w1.y = fixpair(R.m1.y, R.p1l.z, R.p1l.w, R.fl.z, R.fl.w);             \
    w1.z = fixpair(R.m1.z, R.p1h.x, R.p1h.y, R.fh.x, R.fh.y);             \
    w1.w = fixpair(R.m1.w, R.p1h.z, R.p1h.w, R.fh.z, R.fh.w);             \
    *(uint4*)&lds[slot][0][tid * 8]        = w0;                          \
    *(uint4*)&lds[slot][0][4096 + tid * 8] = w1;                          \
  } while (0)

  f32x4 acc[8][4];
#pragma unroll
  for (int i = 0; i < 8; i++)
#pragma unroll
    for (int j = 0; j < 4; j++) acc[i][j] = (f32x4){0.f, 0.f, 0.f, 0.f};

  const int lrow = lane & 15;
  const int kq   = lane >> 4;
  const int kc   = (lrow >> 1) & 3;
  const int coff = ((kq ^ kc) << 3);

  const int NKT = K >> 5;  // 32

  // ---- prologue: B 0..2 DMA'd; slots 0,1 A built via single R; R <- A(2) ----
  STAGE_B2(0, 0);
  STAGE_B2(1, 1);
  STAGE_B2(2, 2);
  LOADA(0);
  asm volatile("s_waitcnt vmcnt(0)" ::: "memory");
  FIXWRITE(0);
  LOADA(1);
  asm volatile("s_waitcnt vmcnt(0)" ::: "memory");
  FIXWRITE(1);
  LOADA(2);  // consumed at iter 0 (guarded by its vmcnt)
  asm volatile("s_waitcnt lgkmcnt(0)" ::: "memory");
  __builtin_amdgcn_sched_barrier(0);
  __builtin_amdgcn_s_barrier();

  for (int kt = 0; kt < NKT; ++kt) {
    const int slot = kt & 3;
    bf16x8 a[8], b[4];
#pragma unroll
    for (int i = 0; i < 8; i++)
      a[i] = *(const bf16x8*)&lds[slot][0][(wr + i * 16 + lrow) * 32 + coff];
#pragma unroll
    for (int j = 0; j < 4; j++)
      b[j] = *(const bf16x8*)&lds[slot][1][(wc + j * 16 + lrow) * 32 + coff];

    if (kt + 3 < NKT) STAGE_B2((kt + 3) & 3, kt + 3);
    __builtin_amdgcn_sched_barrier(0);  // pin DMA issue before the counted wait

    // MFMA first: needs only the auto-lgkm'd frag reads; the wait + fixup
    // VALU + next loads below overlap the matrix pipe.
#pragma unroll
    for (int i = 0; i < 8; i++)
#pragma unroll
      for (int j = 0; j < 4; j++)
        acc[i][j] = __builtin_amdgcn_mfma_f32_16x16x32_bf16(a[i], b[j], acc[i][j], 0, 0, 0);

    if (kt + 2 < NKT) {
      if (kt + 3 < NKT) asm volatile("s_waitcnt vmcnt(2)" ::: "memory");
      else              asm volatile("s_waitcnt vmcnt(0)" ::: "memory");
      __builtin_amdgcn_sched_barrier(0);  // nothing hoists above the wait
      FIXWRITE((kt + 2) & 3);
    }
    if (kt + 3 < NKT) LOADA(kt + 3);

    if (kt < NKT - 1) {
      asm volatile("s_waitcnt lgkmcnt(0)" ::: "memory");
      __builtin_amdgcn_sched_barrier(0);
      __builtin_amdgcn_s_barrier();
    }
  }
#undef FIXWRITE
#undef LOADA
#undef STAGE_B2

  // epilogue: bias + relu, fp32 out
  const int crow = (lane >> 4) << 2;
  const int ccol = lane & 15;
#pragma unroll
  for (int i = 0; i < 8; i++) {
#pragma unroll
    for (int j = 0; j < 4; j++) {
      const int gm = tile_m + wr + i * 16 + crow;
      const int gn = tile_n + wc + j * 16 + ccol;
      const float bv = bias[gn];
#pragma unroll
      for (int r = 0; r < 4; r++) {
        float v = acc[i][j][r] + bv;
        v = fmaxf(v, 0.f);
        Cout[(size_t)(gm + r) * N + gn] = v;
      }
    }
  }
}

extern "C" void kernel_launch(void* const* d_in, const int* in_sizes, int n_in,
                              void* d_out, int out_size, void* d_ws, size_t ws_size,
                              hipStream_t stream) {
  const float* x        = (const float*)d_in[0];
  const float* W_q      = (const float*)d_in[1];
  const float* b_q      = (const float*)d_in[2];
  const float* beta_raw = (const float*)d_in[3];
  const float* W_fc     = (const float*)d_in[4];
  const float* b_fc     = (const float*)d_in[5];

  const int H = 1024;
  const int M = 2048 * 8;              // T*B = 16384 rows
  const size_t MH = (size_t)M * H;     // 16.7M elements

  char* ws = (char*)d_ws;
  u16* x_bf    = (u16*)ws;  ws += MH * 2;                   // 32 MB
  u16* m_loc   = (u16*)ws;  ws += MH * 2;                   // 32 MB
  u16* wq_bf   = (u16*)ws;  ws += (size_t)H * H * 2;        // 2 MB
  u16* wfc_bf  = (u16*)ws;  ws += (size_t)H * H * 2;        // 2 MB
  float* beta  = (float*)ws; ws += 4096;
  float* bpow  = (float*)ws; ws += 33 * 1024 * 4;           // 132 KB
  float* carry = (float*)ws; ws += (size_t)64 * 8192 * 4;   // 2 MB
  float* Fbuf  = (float*)ws; ws += (size_t)64 * 8192 * 4;   // 2 MB

  prep_all<<<(int)(MH / 8 / 256), 256, 0, stream>>>(x, W_q, W_fc, beta_raw,
                                                    x_bf, wq_bf, wfc_bf, beta, bpow);

  // GEMM1 + full in-register segment-local scan (writes m_local + carry)
  gemm_scan<<<256, 512, 0, stream>>>(x_bf, wq_bf, b_q, m_loc, beta, carry, M, H, H);

  // GEMM2 with inline F-fold prologue + cross-segment fixup fused into A-staging
  gemm_fix<<<256, 512, 0, stream>>>(m_loc, wfc_bf, b_fc, (float*)d_out,
                                    bpow, carry, Fbuf, M, H, H);
}

// Round 10
// 240.818 us; speedup vs baseline: 1.0359x; 1.0359x over previous
//
#include <hip/hip_runtime.h>
#include <stdint.h>

typedef unsigned short u16;
typedef __bf16 bf16x8 __attribute__((ext_vector_type(8)));
typedef float f32x4 __attribute__((ext_vector_type(4)));

__device__ __forceinline__ u16 f2bf(float f) {
  union { float f; uint32_t u; } x; x.f = f;
  uint32_t u = x.u;
  u += 0x7fffu + ((u >> 16) & 1u);   // round-to-nearest-even
  return (u16)(u >> 16);
}
__device__ __forceinline__ float bf2f(uint32_t lo16) {
  union { uint32_t u; float f; } x; x.u = lo16 << 16; return x.f;
}
__device__ __forceinline__ float bfhi(uint32_t u) {
  union { uint32_t u; float f; } x; x.u = u & 0xffff0000u; return x.f;
}
// fix one bf16 pair: e_k = m_k + p_k * F_k, repacked to bf16x2
__device__ __forceinline__ uint32_t fixpair(uint32_t m, float p0, float p1,
                                            float F0, float F1) {
  float e0 = fmaf(p0, F0, bf2f(m & 0xffffu));
  float e1 = fmaf(p1, F1, bfhi(m));
  return (uint32_t)f2bf(e0) | ((uint32_t)f2bf(e1) << 16);
}

__device__ __forceinline__ void async_load16(const u16* g, u16* l) {
  __builtin_amdgcn_global_load_lds(
      (const __attribute__((address_space(1))) void*)g,
      (__attribute__((address_space(3))) void*)l,
      16, 0, 0);
}

// ---------------- prep_all: sigmoid(beta)+bpow table + weight/x converts ----------------
// bpow[p][h] = beta_h^p for p = 1..32 (fp32, 132 KB, L2-resident).
__global__ __launch_bounds__(256) void prep_all(const float* __restrict__ x,
                                                const float* __restrict__ Wq,
                                                const float* __restrict__ Wfc,
                                                const float* __restrict__ braw,
                                                u16* __restrict__ xb,
                                                u16* __restrict__ wqb,
                                                u16* __restrict__ wfcb,
                                                float* __restrict__ beta,
                                                float* __restrict__ bpow) {
  int gid = blockIdx.x * 256 + threadIdx.x;
  if (gid < 1024) {
    float b = 1.0f / (1.0f + expf(-braw[gid]));
    beta[gid] = b;
    float w = b;
#pragma unroll 1
    for (int p = 1; p <= 32; p++) { bpow[p * 1024 + gid] = w; w *= b; }
  }
  if (gid < 131072) {
    const int HH = 1024 * 1024;
    int i = gid * 16;
    const float* src = (i < HH) ? (Wq + i) : (Wfc + (i - HH));
    u16* dst = (i < HH) ? (wqb + i) : (wfcb + (i - HH));
#pragma unroll
    for (int c = 0; c < 4; c++) {
      float4 v = *(const float4*)(src + c * 4);
      ushort4 o = {f2bf(v.x), f2bf(v.y), f2bf(v.z), f2bf(v.w)};
      *(ushort4*)(dst + c * 4) = o;
    }
  }
  {
    int i = gid * 8;
    float4 a = *(const float4*)(x + i);
    float4 b = *(const float4*)(x + i + 4);
    ushort4 o0 = {f2bf(a.x), f2bf(a.y), f2bf(a.z), f2bf(a.w)};
    ushort4 o1 = {f2bf(b.x), f2bf(b.y), f2bf(b.z), f2bf(b.w)};
    *(ushort4*)(xb + i) = o0;
    *(ushort4*)(xb + i + 4) = o1;
  }
}

// ---------------- GEMM1 + fused segment-local scan: m_local = localscan(x Wq^T + b) ----
// Ring schedule = R1/R4 harness-verified (256x256 tile, BK=32, 4-deep LDS ring,
// counted vmcnt(8), XCD swizzle). Epilogue computes the FULL segment-local scan
// in-register (one block = one 32t x 8b segment) and writes bf16 m_local + the
// segment carry m(31). Verified passing in R7/R9.
__global__ __launch_bounds__(512, 2) void gemm_scan(const u16* __restrict__ A,
                                                    const u16* __restrict__ B,
                                                    const float* __restrict__ bias,
                                                    u16* __restrict__ Cout,
                                                    const float* __restrict__ beta_arr,
                                                    float* __restrict__ carry_out,
                                                    int M, int N, int K) {
  __shared__ u16 lds[4][2][256 * 32];  // 128 KiB ring

  const int tid  = threadIdx.x;
  const int lane = tid & 63;
  const int wid  = tid >> 6;
  const int wr   = (wid >> 2) * 128;
  const int wc   = (wid & 3) * 64;

  const int bid    = blockIdx.x;
  const int xcd    = bid & 7;
  const int idx    = bid >> 3;
  const int tile_m = ((xcd << 3) | (idx >> 2)) * 256;
  const int tile_n = (idx & 3) * 256;

  const int srow    = tid >> 2;
  const int schunk  = (tid & 3) ^ ((srow >> 1) & 3);
  const u16* gA = A + (size_t)(tile_m + srow) * K + schunk * 8;
  const u16* gB = B + (size_t)(tile_n + srow) * K + schunk * 8;
  const size_t half_stride = (size_t)128 * K;

#define STAGE(slot, kt)                                                   \
  do {                                                                    \
    const size_t k0 = (size_t)(kt) * 32;                                  \
    async_load16(gA + k0,               &lds[slot][0][wid * 512]);        \
    async_load16(gA + k0 + half_stride, &lds[slot][0][4096 + wid * 512]); \
    async_load16(gB + k0,               &lds[slot][1][wid * 512]);        \
    async_load16(gB + k0 + half_stride, &lds[slot][1][4096 + wid * 512]); \
  } while (0)

  f32x4 acc[8][4];
#pragma unroll
  for (int i = 0; i < 8; i++)
#pragma unroll
    for (int j = 0; j < 4; j++) acc[i][j] = (f32x4){0.f, 0.f, 0.f, 0.f};

  const int lrow = lane & 15;
  const int kq   = lane >> 4;
  const int kc   = (lrow >> 1) & 3;
  const int coff = ((kq ^ kc) << 3);

  const int NKT = K >> 5;  // 32

  STAGE(0, 0);
  if (NKT > 1) STAGE(1, 1);
  if (NKT > 2) STAGE(2, 2);
  if (NKT > 2)      asm volatile("s_waitcnt vmcnt(8)" ::: "memory");
  else if (NKT > 1) asm volatile("s_waitcnt vmcnt(4)" ::: "memory");
  else              asm volatile("s_waitcnt vmcnt(0)" ::: "memory");
  __builtin_amdgcn_s_barrier();

  for (int kt = 0; kt < NKT; ++kt) {
    const int slot = kt & 3;
    const u16* As = &lds[slot][0][0];
    const u16* Bs = &lds[slot][1][0];

    bf16x8 a[8], b[4];
#pragma unroll
    for (int i = 0; i < 8; i++)
      a[i] = *(const bf16x8*)&As[(wr + i * 16 + lrow) * 32 + coff];
#pragma unroll
    for (int j = 0; j < 4; j++)
      b[j] = *(const bf16x8*)&Bs[(wc + j * 16 + lrow) * 32 + coff];

    if (kt + 3 < NKT) STAGE((kt + 3) & 3, kt + 3);

    __builtin_amdgcn_s_setprio(1);
#pragma unroll
    for (int i = 0; i < 8; i++)
#pragma unroll
      for (int j = 0; j < 4; j++)
        acc[i][j] = __builtin_amdgcn_mfma_f32_16x16x32_bf16(a[i], b[j], acc[i][j], 0, 0, 0);
    __builtin_amdgcn_s_setprio(0);

    const int ahead = NKT - 1 - kt;
    if (ahead >= 3) {
      asm volatile("s_waitcnt vmcnt(8)" ::: "memory");
      __builtin_amdgcn_s_barrier();
    } else if (ahead == 2) {
      asm volatile("s_waitcnt vmcnt(4)" ::: "memory");
      __builtin_amdgcn_s_barrier();
    } else if (ahead == 1) {
      asm volatile("s_waitcnt vmcnt(0)" ::: "memory");
      __builtin_amdgcn_s_barrier();
    }
  }
#undef STAGE

  // ---------------- fused segment-local scan epilogue ----------------
  const int crow = (lane >> 4) << 2;
  const int ccol = lane & 15;
  const int c4   = lane >> 4;
  const int kap  = c4 >> 1;
  const int Wh   = wr >> 7;
  float* sm15 = (float*)&lds[0][0][0];  // [8][256] fp32, 8 KB (ring slot 0)

  // Phase A: local (t-half) scan, in place in acc
#pragma unroll
  for (int j = 0; j < 4; j++) {
    const int gn = tile_n + wc + j * 16 + ccol;
    const float bv = bias[gn];
    const float be = beta_arr[gn];
    const float be2 = be * be;
#pragma unroll
    for (int r = 0; r < 4; r++) {
      float S[8], R[8];
      S[0] = acc[0][j][r] + bv;
#pragma unroll
      for (int i = 1; i < 8; i++) S[i] = fmaf(be2, S[i - 1], acc[i][j][r] + bv);
#pragma unroll
      for (int i = 0; i < 8; i++) R[i] = __shfl_xor(S[i], 32);
      acc[0][j][r] = kap ? fmaf(be, R[0], S[0]) : S[0];
#pragma unroll
      for (int i = 1; i < 8; i++)
        acc[i][j][r] = fmaf(be, kap ? R[i] : R[i - 1], S[i]);
    }
  }
  // Phase B: export m(15)
  if (Wh == 0 && kap == 1) {
#pragma unroll
    for (int j = 0; j < 4; j++)
#pragma unroll
      for (int r = 0; r < 4; r++) {
        const int bb = ((c4 << 2) + r) & 7;
        sm15[bb * 256 + wc + j * 16 + ccol] = acc[7][j][r];
      }
  }
  __syncthreads();
  // Phase C: upper half adds beta^{2i+kap+1} * m(15)
  if (Wh == 1) {
#pragma unroll
    for (int j = 0; j < 4; j++) {
      const int hl = wc + j * 16 + ccol;
      const float be = beta_arr[tile_n + hl];
      const float be2 = be * be;
#pragma unroll
      for (int r = 0; r < 4; r++) {
        const int bb = ((c4 << 2) + r) & 7;
        const float v = sm15[bb * 256 + hl];
        float f = kap ? be2 : be;
#pragma unroll
        for (int i = 0; i < 8; i++) {
          acc[i][j][r] = fmaf(f, v, acc[i][j][r]);
          f *= be2;
        }
      }
    }
  }
  // Phase D: store bf16 m_local (+ per-segment carry from registers)
#pragma unroll
  for (int i = 0; i < 8; i++) {
#pragma unroll
    for (int j = 0; j < 4; j++) {
      const int gm = tile_m + wr + i * 16 + crow;
      const int gn = tile_n + wc + j * 16 + ccol;
#pragma unroll
      for (int r = 0; r < 4; r++)
        Cout[(size_t)(gm + r) * N + gn] = f2bf(acc[i][j][r]);
    }
  }
  if (Wh == 1 && kap == 1) {
    const int seg = tile_m >> 8;
#pragma unroll
    for (int j = 0; j < 4; j++) {
      const int hl = wc + j * 16 + ccol;
#pragma unroll
      for (int r = 0; r < 4; r++) {
        const int bb = ((c4 << 2) + r) & 7;
        carry_out[(size_t)seg * 8192 + bb * 1024 + tile_n + hl] = acc[7][j][r];
      }
    }
  }
}

// ---------------- ffold: F[s] = beta^32 * F[s-1] + carry[s-1], F[0] = 0 ----------------
// Verified R7. b32 indexed by h-quad (per-h table).
__global__ __launch_bounds__(256) void ffold(const float4* __restrict__ carry4,
                                             const float* __restrict__ bpow,
                                             float4* __restrict__ Fbuf) {
  const int cq = blockIdx.x * 256 + threadIdx.x;  // 0..2047  (= b*256 + h/4)
  const int hq = cq & 255;                        // h quad: h = hq*4 .. hq*4+3
  const float4 b32 = *(const float4*)&bpow[32 * 1024 + hq * 4];
  float4 F = make_float4(0.f, 0.f, 0.f, 0.f);
  for (int s = 0; s < 64; s++) {
    Fbuf[(size_t)s * 2048 + cq] = F;
    float4 c = carry4[(size_t)s * 2048 + cq];
    F.x = fmaf(b32.x, F.x, c.x);
    F.y = fmaf(b32.y, F.y, c.y);
    F.z = fmaf(b32.z, F.z, c.z);
    F.w = fmaf(b32.w, F.w, c.w);
  }
}

// ---------------- mfix: m = m_local + bpow[t_loc+1] * F[seg]  (pure streaming) ----------
// 64 MB HBM traffic (32 read + 32 write), bpow/F are L2-resident. No serial
// chains -- replaces R4's scan_fuse (Horner rescan) and R5-R9's in-GEMM fixup
// (reg-staging, measured net-negative both ways).
// Row r = t*8 + b; seg = r>>8, t_loc = (r&255)>>3, b = r&7.
__global__ __launch_bounds__(256) void mfix(const uint4* __restrict__ mloc,
                                            const float* __restrict__ bpow,
                                            const float* __restrict__ Fbuf,
                                            uint4* __restrict__ mout) {
  const int stride = gridDim.x * 256;
  const int total  = 16384 * 128;           // rows x (1024/8) uint4 per row
  for (int idx = blockIdx.x * 256 + threadIdx.x; idx < total; idx += stride) {
    const int r   = idx >> 7;
    const int hq  = idx & 127;              // h/8
    const int seg = r >> 8;
    const int rl  = r & 255;
    const int tl  = rl >> 3;
    const int b   = rl & 7;
    const float* p = bpow + (size_t)(tl + 1) * 1024 + hq * 8;
    const float* f = Fbuf + (size_t)seg * 8192 + b * 1024 + hq * 8;
    const float4 p0 = *(const float4*)p,       p1 = *(const float4*)(p + 4);
    const float4 f0 = *(const float4*)f,       f1 = *(const float4*)(f + 4);
    const uint4 m = mloc[idx];
    uint4 o;
    o.x = fixpair(m.x, p0.x, p0.y, f0.x, f0.y);
    o.y = fixpair(m.y, p0.z, p0.w, f0.z, f0.w);
    o.z = fixpair(m.z, p1.x, p1.y, f1.x, f1.y);
    o.w = fixpair(m.w, p1.z, p1.w, f1.z, f1.w);
    mout[idx] = o;
  }
}

// ---------------- GEMM2: relu(m Wfc^T + b_fc), fp32 out ----------------
// Byte-identical schedule to R4's measured 45.5-us gemm256<1,0,0>: DMA ring,
// counted vmcnt(8), XCD swizzle. No staging-fused work (R5-R9 lesson).
__global__ __launch_bounds__(512, 2) void gemm_relu(const u16* __restrict__ A,
                                                    const u16* __restrict__ B,
                                                    const float* __restrict__ bias,
                                                    float* __restrict__ Cout,
                                                    int M, int N, int K) {
  __shared__ u16 lds[4][2][256 * 32];  // 128 KiB ring

  const int tid  = threadIdx.x;
  const int lane = tid & 63;
  const int wid  = tid >> 6;
  const int wr   = (wid >> 2) * 128;
  const int wc   = (wid & 3) * 64;

  const int bid    = blockIdx.x;
  const int xcd    = bid & 7;
  const int idx    = bid >> 3;
  const int tile_m = ((xcd << 3) | (idx >> 2)) * 256;
  const int tile_n = (idx & 3) * 256;

  const int srow    = tid >> 2;
  const int schunk  = (tid & 3) ^ ((srow >> 1) & 3);
  const u16* gA = A + (size_t)(tile_m + srow) * K + schunk * 8;
  const u16* gB = B + (size_t)(tile_n + srow) * K + schunk * 8;
  const size_t half_stride = (size_t)128 * K;

#define STAGE(slot, kt)                                                   \
  do {                                                                    \
    const size_t k0 = (size_t)(kt) * 32;                                  \
    async_load16(gA + k0,               &lds[slot][0][wid * 512]);        \
    async_load16(gA + k0 + half_stride, &lds[slot][0][4096 + wid * 512]); \
    async_load16(gB + k0,               &lds[slot][1][wid * 512]);        \
    async_load16(gB + k0 + half_stride, &lds[slot][1][4096 + wid * 512]); \
  } while (0)

  f32x4 acc[8][4];
#pragma unroll
  for (int i = 0; i < 8; i++)
#pragma unroll
    for (int j = 0; j < 4; j++) acc[i][j] = (f32x4){0.f, 0.f, 0.f, 0.f};

  const int lrow = lane & 15;
  const int kq   = lane >> 4;
  const int kc   = (lrow >> 1) & 3;
  const int coff = ((kq ^ kc) << 3);

  const int NKT = K >> 5;  // 32

  STAGE(0, 0);
  if (NKT > 1) STAGE(1, 1);
  if (NKT > 2) STAGE(2, 2);
  if (NKT > 2)      asm volatile("s_waitcnt vmcnt(8)" ::: "memory");
  else if (NKT > 1) asm volatile("s_waitcnt vmcnt(4)" ::: "memory");
  else              asm volatile("s_waitcnt vmcnt(0)" ::: "memory");
  __builtin_amdgcn_s_barrier();

  for (int kt = 0; kt < NKT; ++kt) {
    const int slot = kt & 3;
    const u16* As = &lds[slot][0][0];
    const u16* Bs = &lds[slot][1][0];

    bf16x8 a[8], b[4];
#pragma unroll
    for (int i = 0; i < 8; i++)
      a[i] = *(const bf16x8*)&As[(wr + i * 16 + lrow) * 32 + coff];
#pragma unroll
    for (int j = 0; j < 4; j++)
      b[j] = *(const bf16x8*)&Bs[(wc + j * 16 + lrow) * 32 + coff];

    if (kt + 3 < NKT) STAGE((kt + 3) & 3, kt + 3);

    __builtin_amdgcn_s_setprio(1);
#pragma unroll
    for (int i = 0; i < 8; i++)
#pragma unroll
      for (int j = 0; j < 4; j++)
        acc[i][j] = __builtin_amdgcn_mfma_f32_16x16x32_bf16(a[i], b[j], acc[i][j], 0, 0, 0);
    __builtin_amdgcn_s_setprio(0);

    const int ahead = NKT - 1 - kt;
    if (ahead >= 3) {
      asm volatile("s_waitcnt vmcnt(8)" ::: "memory");
      __builtin_amdgcn_s_barrier();
    } else if (ahead == 2) {
      asm volatile("s_waitcnt vmcnt(4)" ::: "memory");
      __builtin_amdgcn_s_barrier();
    } else if (ahead == 1) {
      asm volatile("s_waitcnt vmcnt(0)" ::: "memory");
      __builtin_amdgcn_s_barrier();
    }
  }
#undef STAGE

  // C/D layout: col = lane&15, row = (lane>>4)*4 + r  [measured m89/m91]
  const int crow = (lane >> 4) << 2;
  const int ccol = lane & 15;
#pragma unroll
  for (int i = 0; i < 8; i++) {
#pragma unroll
    for (int j = 0; j < 4; j++) {
      const int gm = tile_m + wr + i * 16 + crow;
      const int gn = tile_n + wc + j * 16 + ccol;
      const float bv = bias[gn];
#pragma unroll
      for (int r = 0; r < 4; r++) {
        float v = acc[i][j][r] + bv;
        v = fmaxf(v, 0.f);
        Cout[(size_t)(gm + r) * N + gn] = v;
      }
    }
  }
}

extern "C" void kernel_launch(void* const* d_in, const int* in_sizes, int n_in,
                              void* d_out, int out_size, void* d_ws, size_t ws_size,
                              hipStream_t stream) {
  const float* x        = (const float*)d_in[0];
  const float* W_q      = (const float*)d_in[1];
  const float* b_q      = (const float*)d_in[2];
  const float* beta_raw = (const float*)d_in[3];
  const float* W_fc     = (const float*)d_in[4];
  const float* b_fc     = (const float*)d_in[5];

  const int H = 1024;
  const int M = 2048 * 8;              // T*B = 16384 rows
  const size_t MH = (size_t)M * H;     // 16.7M elements

  char* ws = (char*)d_ws;
  u16* x_bf    = (u16*)ws;  ws += MH * 2;                   // 32 MB
  u16* m_loc   = (u16*)ws;  ws += MH * 2;                   // 32 MB
  u16* m_fix   = (u16*)ws;  ws += MH * 2;                   // 32 MB
  u16* wq_bf   = (u16*)ws;  ws += (size_t)H * H * 2;        // 2 MB
  u16* wfc_bf  = (u16*)ws;  ws += (size_t)H * H * 2;        // 2 MB
  float* beta  = (float*)ws; ws += 4096;
  float* bpow  = (float*)ws; ws += 33 * 1024 * 4;           // 132 KB
  float* carry = (float*)ws; ws += (size_t)64 * 8192 * 4;   // 2 MB
  float* Fbuf  = (float*)ws; ws += (size_t)64 * 8192 * 4;   // 2 MB

  prep_all<<<(int)(MH / 8 / 256), 256, 0, stream>>>(x, W_q, W_fc, beta_raw,
                                                    x_bf, wq_bf, wfc_bf, beta, bpow);

  // GEMM1 + full in-register segment-local scan (writes m_local + carry)
  gemm_scan<<<256, 512, 0, stream>>>(x_bf, wq_bf, b_q, m_loc, beta, carry, M, H, H);

  // tiny: fold carries into per-segment prefixes F
  ffold<<<8, 256, 0, stream>>>((const float4*)carry, bpow, (float4*)Fbuf);

  // streaming cross-segment fixup (pure BW, no serial chains)
  mfix<<<2048, 256, 0, stream>>>((const uint4*)m_loc, bpow, Fbuf, (uint4*)m_fix);

  // GEMM2: plain verified ring
  gemm_relu<<<256, 512, 0, stream>>>(m_fix, wfc_bf, b_fc, (float*)d_out, M, H, H);
}